// Round 15
// baseline (440.591 us; speedup 1.0000x reference)
//
#include <hip/hip_runtime.h>
#include <hip/hip_bf16.h>
#include <math.h>

#define NN 50000
#define EE 800000
#define GG 50
#define FIN 64
#define HID 128
#define EMB 64
#define NCLS 6
#define EPSBN 1e-5f
#define NEG 0.2f
#define MAXD 64   // max in-degree bucket (deg ~ Poisson(16); P(>=64) ~ 1e-55)
#define PB 8      // pool blocks per graph

__device__ __forceinline__ float lrelu(float x){ return fmaxf(x, NEG * x); }
__device__ __forceinline__ float bf16lo(unsigned u){ return __uint_as_float(u << 16); }
__device__ __forceinline__ float bf16hi(unsigned u){ return __uint_as_float(u & 0xffff0000u); }
__device__ __forceinline__ unsigned f2bf_bits(float f){
    unsigned u = __float_as_uint(f);
    return (u + 0x7fffu + ((u >> 16) & 1u)) >> 16;   // RNE
}

// ---- single-pass bucket scatter: 1 atomic/edge ---------------------------
// combo[d] accumulates: count in bits [40..63], sum(ea)*2^20 in bits [0..39]
__global__ void k_scatter(const int* __restrict__ ei, const float* __restrict__ ea,
                          unsigned long long* __restrict__ combo,
                          unsigned* __restrict__ epack) {
    int e = blockIdx.x * 256 + threadIdx.x;
    if (e < EE) {
        int d = ei[EE + e];
        int s = ei[e];
        float eaf = ea[e];
        unsigned long long add = (1ULL << 40) | (unsigned long long)(eaf * 1048576.0f);
        unsigned long long old = atomicAdd(&combo[d], add);
        int pos = (int)(old >> 40);
        epack[d * MAXD + pos] = ((unsigned)s << 16) | f2bf_bits(eaf);
    }
}

// decode combo -> deg, loopattr ; graph boundaries from sorted batch
__global__ void k_prep(const unsigned long long* __restrict__ combo,
                       int* __restrict__ deg, float* __restrict__ loopattr,
                       const int* __restrict__ batch, int* __restrict__ gstart) {
    int n = blockIdx.x * 256 + threadIdx.x;
    if (n < NN) {
        unsigned long long c = combo[n];
        int cnt = (int)(c >> 40);
        float easum = (float)(c & ((1ULL << 40) - 1)) * (1.0f / 1048576.0f);
        deg[n] = cnt;
        loopattr[n] = cnt > 0 ? easum / (float)cnt : 0.f;
        int b = batch[n];
        int prev = (n == 0) ? -1 : batch[n - 1];
        for (int g = prev + 1; g <= b; g++) gstart[g] = n;
        if (n == NN - 1) {
            for (int g = b + 1; g <= GG; g++) gstart[g] = NN;
        }
    }
}

// ---- GEMM 1: 8 rows/block; k-unroll 4, b128 LDS broadcast ---------------
#define G1R 8
__global__ void k_gemm1(const float* __restrict__ x,
                        const float* __restrict__ Wl, const float* __restrict__ bl,
                        const float* __restrict__ Wr, const float* __restrict__ br,
                        __hip_bfloat16* __restrict__ xlh, float* __restrict__ xr) {
    __shared__ float xs[G1R][FIN];
    int rb = blockIdx.x * G1R;
    int t = threadIdx.x;  // 256
    for (int i = t; i < G1R * FIN; i += 256) {
        int r = i >> 6, k = i & 63;
        xs[r][k] = x[(rb + r) * FIN + k];
    }
    __syncthreads();
    bool isL = t < HID;
    int c = isL ? t : t - HID;
    const float* W = isL ? Wl : Wr;
    float bias = isL ? bl[c] : br[c];
    float acc[G1R];
#pragma unroll
    for (int r = 0; r < G1R; r++) acc[r] = bias;
    for (int k = 0; k < FIN; k += 4) {
        float w0 = W[(k + 0) * HID + c];
        float w1 = W[(k + 1) * HID + c];
        float w2 = W[(k + 2) * HID + c];
        float w3 = W[(k + 3) * HID + c];
#pragma unroll
        for (int r = 0; r < G1R; r++) {
            float4 xv = *reinterpret_cast<const float4*>(&xs[r][k]);
            acc[r] = fmaf(xv.x, w0, fmaf(xv.y, w1, fmaf(xv.z, w2, fmaf(xv.w, w3, acc[r]))));
        }
    }
    if (isL) {
#pragma unroll
        for (int r = 0; r < G1R; r++) xlh[(rb + r) * HID + c] = __float2bfloat16(acc[r]);
    } else {
#pragma unroll
        for (int r = 0; r < G1R; r++) xr[(rb + r) * HID + c] = acc[r];
    }
}

// ---- GATv2 layer 1: half-wave, 4 streams/half (8 edges in flight) -------
// exp-shift cancels in the division; |logit| <~ 10 so exp is f32-safe.
__global__ void k_gat1(const float* __restrict__ loopattr, const int* __restrict__ deg,
                       const unsigned* __restrict__ epack,
                       const __hip_bfloat16* __restrict__ xlh, const float* __restrict__ xr1,
                       const float* __restrict__ We1, const float* __restrict__ att1,
                       const float* __restrict__ bias1, float* __restrict__ out1) {
    int wid = (blockIdx.x * blockDim.x + threadIdx.x) >> 6;
    int lane = threadIdx.x & 63;
    if (wid >= NN) return;
    int n = wid;
    int half = lane >> 5;        // 0 or 1
    int cl   = lane & 31;        // channel-lane
    int c0   = 4 * cl;           // channels c0..c0+3 ; head = cl>>2
    float4 xrv = *reinterpret_cast<const float4*>(&xr1[n * HID + c0]);
    float4 we  = *reinterpret_cast<const float4*>(&We1[c0]);
    float4 at  = *reinterpret_cast<const float4*>(&att1[c0]);
    float la = loopattr[n];
    int beg = n * MAXD, end = beg + deg[n];

    float s0 = 0.f, a00 = 0.f, a01 = 0.f, a02 = 0.f, a03 = 0.f;
    float s1 = 0.f, a10 = 0.f, a11 = 0.f, a12 = 0.f, a13 = 0.f;
    float s2 = 0.f, a20 = 0.f, a21 = 0.f, a22 = 0.f, a23 = 0.f;
    float s3 = 0.f, a30 = 0.f, a31 = 0.f, a32 = 0.f, a33 = 0.f;

#define UPD1(U, EA, SS, A0, A1, A2, A3)                                       \
    {                                                                          \
        float x0 = bf16lo((U).x), x1 = bf16hi((U).x);                          \
        float x2 = bf16lo((U).y), x3 = bf16hi((U).y);                          \
        float g0 = lrelu(x0 + fmaf(EA, we.x, xrv.x));                          \
        float g1 = lrelu(x1 + fmaf(EA, we.y, xrv.y));                          \
        float g2 = lrelu(x2 + fmaf(EA, we.z, xrv.z));                          \
        float g3 = lrelu(x3 + fmaf(EA, we.w, xrv.w));                          \
        float part = g0 * at.x + g1 * at.y + g2 * at.z + g3 * at.w;            \
        part += __shfl_xor(part, 1);                                           \
        part += __shfl_xor(part, 2);                                           \
        float p = __expf(part);                                                \
        SS += p;                                                               \
        A0 = fmaf(x0, p, A0);                                                  \
        A1 = fmaf(x1, p, A1);                                                  \
        A2 = fmaf(x2, p, A2);                                                  \
        A3 = fmaf(x3, p, A3);                                                  \
    }

    for (int base = beg; base < end; base += 8) {
        int i = base + half * 4;                      // 16B-aligned (MAXD=64)
        uint4 q = *reinterpret_cast<const uint4*>(&epack[i]);  // always in padded row
        bool b0 = i + 0 < end, b1 = i + 1 < end, b2 = i + 2 < end, b3 = i + 3 < end;
        uint2 u0 = b0 ? *reinterpret_cast<const uint2*>(&xlh[(q.x >> 16) * HID + c0]) : make_uint2(0, 0);
        uint2 u1 = b1 ? *reinterpret_cast<const uint2*>(&xlh[(q.y >> 16) * HID + c0]) : make_uint2(0, 0);
        uint2 u2 = b2 ? *reinterpret_cast<const uint2*>(&xlh[(q.z >> 16) * HID + c0]) : make_uint2(0, 0);
        uint2 u3 = b3 ? *reinterpret_cast<const uint2*>(&xlh[(q.w >> 16) * HID + c0]) : make_uint2(0, 0);
        if (b0) UPD1(u0, bf16lo(q.x), s0, a00, a01, a02, a03);
        if (b1) UPD1(u1, bf16lo(q.y), s1, a10, a11, a12, a13);
        if (b2) UPD1(u2, bf16lo(q.z), s2, a20, a21, a22, a23);
        if (b3) UPD1(u3, bf16lo(q.w), s3, a30, a31, a32, a33);
    }
    if (half == 1) {   // self-loop in half B, stream 0
        uint2 u = *reinterpret_cast<const uint2*>(&xlh[n * HID + c0]);
        UPD1(u, la, s0, a00, a01, a02, a03);
    }
#undef UPD1

    // merge 4 streams + cross-half (plain sums)
    s0 += s1 + s2 + s3;
    a00 += a10 + a20 + a30;
    a01 += a11 + a21 + a31;
    a02 += a12 + a22 + a32;
    a03 += a13 + a23 + a33;
    s0  += __shfl_xor(s0, 32);
    a00 += __shfl_xor(a00, 32);
    a01 += __shfl_xor(a01, 32);
    a02 += __shfl_xor(a02, 32);
    a03 += __shfl_xor(a03, 32);
    if (half == 0) {
        float4 bi = *reinterpret_cast<const float4*>(&bias1[c0]);
        float inv = 1.f / s0;
        float4 o = make_float4(a00 * inv + bi.x, a01 * inv + bi.y,
                               a02 * inv + bi.z, a03 * inv + bi.w);
        *reinterpret_cast<float4*>(&out1[n * HID + c0]) = o;
    }
}

// ---- BatchNorm stats (float4 channels) + finalize -----------------------
template <int CH>
__global__ void k_bnstat(const float* __restrict__ xin, float* __restrict__ sums,
                         float* __restrict__ sumsq) {
    constexpr int CG = CH / 4;        // 32 (HID) or 16 (EMB) channel-groups
    constexpr int RPI = 256 / CG;     // 8 or 16 rows per block-iter
    int t = threadIdx.x;
    int cg = t % CG;
    int rl = t / CG;
    float4 s = make_float4(0.f, 0.f, 0.f, 0.f);
    float4 q = make_float4(0.f, 0.f, 0.f, 0.f);
    for (int r = blockIdx.x * RPI + rl; r < NN; r += gridDim.x * RPI) {
        float4 v = *reinterpret_cast<const float4*>(&xin[r * CH + cg * 4]);
        s.x += v.x; s.y += v.y; s.z += v.z; s.w += v.w;
        q.x = fmaf(v.x, v.x, q.x); q.y = fmaf(v.y, v.y, q.y);
        q.z = fmaf(v.z, v.z, q.z); q.w = fmaf(v.w, v.w, q.w);
    }
    __shared__ float4 sh[256], shq[256];
    sh[t] = s; shq[t] = q;
    __syncthreads();
    if (t < CG) {
        float4 ts = make_float4(0.f, 0.f, 0.f, 0.f);
        float4 tq = make_float4(0.f, 0.f, 0.f, 0.f);
        for (int i = t; i < 256; i += CG) {
            float4 a = sh[i], b = shq[i];
            ts.x += a.x; ts.y += a.y; ts.z += a.z; ts.w += a.w;
            tq.x += b.x; tq.y += b.y; tq.z += b.z; tq.w += b.w;
        }
        atomicAdd(&sums[t * 4 + 0], ts.x);
        atomicAdd(&sums[t * 4 + 1], ts.y);
        atomicAdd(&sums[t * 4 + 2], ts.z);
        atomicAdd(&sums[t * 4 + 3], ts.w);
        atomicAdd(&sumsq[t * 4 + 0], tq.x);
        atomicAdd(&sumsq[t * 4 + 1], tq.y);
        atomicAdd(&sumsq[t * 4 + 2], tq.z);
        atomicAdd(&sumsq[t * 4 + 3], tq.w);
    }
}

template <int CH>
__global__ void k_bnfin(const float* __restrict__ sums, const float* __restrict__ sumsq,
                        const float* __restrict__ gamma, const float* __restrict__ beta,
                        float* __restrict__ a, float* __restrict__ b) {
    int c = threadIdx.x;
    if (c < CH) {
        float mean = sums[c] / (float)NN;
        float var  = sumsq[c] / (float)NN - mean * mean;
        float rs = rsqrtf(var + EPSBN);
        float aa = gamma[c] * rs;
        a[c] = aa;
        b[c] = beta[c] - mean * aa;
    }
}

// ---- GEMM 2: 8 rows/block, fused BN+ReLU input; k-unroll 4 --------------
#define G2R 8
__global__ void k_gemm2(const float* __restrict__ out1, const float* __restrict__ a1,
                        const float* __restrict__ b1,
                        const float* __restrict__ Wl, const float* __restrict__ bl,
                        const float* __restrict__ Wr, const float* __restrict__ br,
                        __hip_bfloat16* __restrict__ xlh, float* __restrict__ xr2) {
    __shared__ float hs[G2R][HID];
    int rb = blockIdx.x * G2R;
    int t = threadIdx.x;  // 256
    for (int i = t; i < G2R * HID; i += 256) {
        int r = i >> 7, k = i & 127;
        float v = out1[(rb + r) * HID + k] * a1[k] + b1[k];
        hs[r][k] = v > 0.f ? v : 0.f;
    }
    __syncthreads();
    int c = t & 127;
    int rg = (t >> 7) * 4;  // 0 or 4
    bool isL = c < EMB;
    int cc = isL ? c : c - EMB;
    const float* W = isL ? Wl : Wr;
    float bias = isL ? bl[cc] : br[cc];
    float acc[4] = {bias, bias, bias, bias};
    for (int k = 0; k < HID; k += 4) {
        float w0 = W[(k + 0) * EMB + cc];
        float w1 = W[(k + 1) * EMB + cc];
        float w2 = W[(k + 2) * EMB + cc];
        float w3 = W[(k + 3) * EMB + cc];
#pragma unroll
        for (int r = 0; r < 4; r++) {
            float4 hv = *reinterpret_cast<const float4*>(&hs[rg + r][k]);
            acc[r] = fmaf(hv.x, w0, fmaf(hv.y, w1, fmaf(hv.z, w2, fmaf(hv.w, w3, acc[r]))));
        }
    }
    if (isL) {
#pragma unroll
        for (int r = 0; r < 4; r++) xlh[(rb + rg + r) * EMB + cc] = __float2bfloat16(acc[r]);
    } else {
#pragma unroll
        for (int r = 0; r < 4; r++) xr2[(rb + rg + r) * EMB + cc] = acc[r];
    }
}

// ---- GATv2 layer 2: half-wave, 4 streams/half (8 edges in flight) -------
__global__ void k_gat2(const float* __restrict__ loopattr, const int* __restrict__ deg,
                       const unsigned* __restrict__ epack,
                       const __hip_bfloat16* __restrict__ xlh, const float* __restrict__ xr2,
                       const float* __restrict__ We2, const float* __restrict__ att2,
                       const float* __restrict__ bias2, float* __restrict__ out2) {
    int wid = (blockIdx.x * blockDim.x + threadIdx.x) >> 6;
    int lane = threadIdx.x & 63;
    if (wid >= NN) return;
    int n = wid;
    int half = lane >> 5;
    int cl   = lane & 31;
    int c0   = 2 * cl;
    float2 xrv = *reinterpret_cast<const float2*>(&xr2[n * EMB + c0]);
    float2 we  = *reinterpret_cast<const float2*>(&We2[c0]);
    float2 at  = *reinterpret_cast<const float2*>(&att2[c0]);
    float la = loopattr[n];
    int beg = n * MAXD, end = beg + deg[n];

    float s0 = 0.f, a00 = 0.f, a01 = 0.f;
    float s1 = 0.f, a10 = 0.f, a11 = 0.f;
    float s2 = 0.f, a20 = 0.f, a21 = 0.f;
    float s3 = 0.f, a30 = 0.f, a31 = 0.f;

#define UPD2(U, EA, SS, A0, A1)                                               \
    {                                                                          \
        float x0 = bf16lo(U), x1 = bf16hi(U);                                  \
        float g0 = lrelu(x0 + fmaf(EA, we.x, xrv.x));                          \
        float g1 = lrelu(x1 + fmaf(EA, we.y, xrv.y));                          \
        float part = g0 * at.x + g1 * at.y;                                    \
        part += __shfl_xor(part, 1);                                           \
        part += __shfl_xor(part, 2);                                           \
        part += __shfl_xor(part, 4);                                           \
        part += __shfl_xor(part, 8);                                           \
        part += __shfl_xor(part, 16);                                          \
        float p = __expf(part);                                                \
        SS += p;                                                               \
        A0 = fmaf(x0, p, A0);                                                  \
        A1 = fmaf(x1, p, A1);                                                  \
    }

    for (int base = beg; base < end; base += 8) {
        int i = base + half * 4;
        uint4 q = *reinterpret_cast<const uint4*>(&epack[i]);
        bool b0 = i + 0 < end, b1 = i + 1 < end, b2 = i + 2 < end, b3 = i + 3 < end;
        unsigned u0 = b0 ? *reinterpret_cast<const unsigned*>(&xlh[(q.x >> 16) * EMB + c0]) : 0u;
        unsigned u1 = b1 ? *reinterpret_cast<const unsigned*>(&xlh[(q.y >> 16) * EMB + c0]) : 0u;
        unsigned u2 = b2 ? *reinterpret_cast<const unsigned*>(&xlh[(q.z >> 16) * EMB + c0]) : 0u;
        unsigned u3 = b3 ? *reinterpret_cast<const unsigned*>(&xlh[(q.w >> 16) * EMB + c0]) : 0u;
        if (b0) UPD2(u0, bf16lo(q.x), s0, a00, a01);
        if (b1) UPD2(u1, bf16lo(q.y), s1, a10, a11);
        if (b2) UPD2(u2, bf16lo(q.z), s2, a20, a21);
        if (b3) UPD2(u3, bf16lo(q.w), s3, a30, a31);
    }
    if (half == 1) {   // self-loop in half B, stream 0
        unsigned u = *reinterpret_cast<const unsigned*>(&xlh[n * EMB + c0]);
        UPD2(u, la, s0, a00, a01);
    }
#undef UPD2

    s0 += s1 + s2 + s3;
    a00 += a10 + a20 + a30;
    a01 += a11 + a21 + a31;
    s0  += __shfl_xor(s0, 32);
    a00 += __shfl_xor(a00, 32);
    a01 += __shfl_xor(a01, 32);
    if (half == 0) {
        float inv = 1.f / s0;
        float2 o = make_float2(a00 * inv + bias2[c0], a01 * inv + bias2[c0 + 1]);
        *reinterpret_cast<float2*>(&out2[n * EMB + c0]) = o;
    }
}

// ---- fused BN-apply + ReLU + node_emb write + pool partial sums ----------
__global__ void k_poolA(const float* __restrict__ out2, const float* __restrict__ a2,
                        const float* __restrict__ b2, const int* __restrict__ gstart,
                        float* __restrict__ nodeemb, float* __restrict__ domsum) {
    int g = blockIdx.x / PB;
    int sb = blockIdx.x % PB;
    int t = threadIdx.x;  // 256
    int c = t & 63, rl = t >> 6;
    int beg = gstart[g], end = gstart[g + 1];
    float s = 0.f;
    for (int r = beg + sb * 4 + rl; r < end; r += PB * 4) {
        float v = out2[r * EMB + c] * a2[c] + b2[c];
        v = v > 0.f ? v : 0.f;
        nodeemb[r * EMB + c] = v;
        s += v;
    }
    __shared__ float sh[256];
    sh[t] = s;
    __syncthreads();
    if (t < EMB) {
        float tot = sh[t] + sh[t + 64] + sh[t + 128] + sh[t + 192];
        atomicAdd(&domsum[g * EMB + t], tot);
    }
}

__global__ void k_logits(const float* __restrict__ domsum, const int* __restrict__ gstart,
                         const float* __restrict__ Wc, const float* __restrict__ bc,
                         float* __restrict__ dom, float* __restrict__ logits) {
    int g = blockIdx.x;   // 50 blocks x 64 threads
    int t = threadIdx.x;
    __shared__ float dsh[EMB];
    float cf = (float)(gstart[g + 1] - gstart[g]);
    if (cf < 1.f) cf = 1.f;
    float d = domsum[g * EMB + t] / cf;
    dsh[t] = d;
    dom[g * EMB + t] = d;
    __syncthreads();
    if (t < NCLS) {
        float acc = bc[t];
        for (int k = 0; k < EMB; k++) acc += dsh[k] * Wc[k * NCLS + t];
        logits[g * NCLS + t] = acc;
    }
}

extern "C" void kernel_launch(void* const* d_in, const int* in_sizes, int n_in,
                              void* d_out, int out_size, void* d_ws, size_t ws_size,
                              hipStream_t stream) {
    const float* x     = (const float*)d_in[0];
    const int*   ei    = (const int*)d_in[1];
    const float* ea    = (const float*)d_in[2];
    const int*   batch = (const int*)d_in[3];
    const float* Wl1 = (const float*)d_in[4];
    const float* bl1 = (const float*)d_in[5];
    const float* Wr1 = (const float*)d_in[6];
    const float* br1 = (const float*)d_in[7];
    const float* We1 = (const float*)d_in[8];
    const float* att1 = (const float*)d_in[9];
    const float* bias1 = (const float*)d_in[10];
    const float* Wl2 = (const float*)d_in[11];
    const float* bl2 = (const float*)d_in[12];
    const float* Wr2 = (const float*)d_in[13];
    const float* br2 = (const float*)d_in[14];
    const float* We2 = (const float*)d_in[15];
    const float* att2 = (const float*)d_in[16];
    const float* bias2 = (const float*)d_in[17];
    const float* gamma1 = (const float*)d_in[18];
    const float* beta1  = (const float*)d_in[19];
    const float* gamma2 = (const float*)d_in[20];
    const float* beta2  = (const float*)d_in[21];
    const float* Wc = (const float*)d_in[22];
    const float* bc = (const float*)d_in[23];

    float* out_logits = (float*)d_out;                 // [50,6]
    float* out_dom    = out_logits + GG * NCLS;        // [50,64]
    float* out_emb    = out_dom + GG * EMB;            // [50000,64]

    char* ws = (char*)d_ws;
    const size_t SZF = (size_t)NN * HID * sizeof(float);           // 25.6 MB
    const size_t SZH = (size_t)NN * HID * sizeof(__hip_bfloat16);  // 12.8 MB
    const size_t SZE = (size_t)NN * MAXD * sizeof(unsigned);       // 12.8 MB
    __hip_bfloat16* xl1h = (__hip_bfloat16*)(ws);
    float* xr1  = (float*)(ws + SZH);
    float* out1 = (float*)(ws + SZH + SZF);
    __hip_bfloat16* xl2h = xl1h;   // k_gemm2 runs after k_gat1 (last reader of xl1h)
    float* xr2  = xr1;             // k_gemm2 runs after k_gat1 (last reader of xr1)
    float* out2 = out1;            // k_gat2 runs after k_gemm2 (last reader of out1)
    unsigned* epack = (unsigned*)(ws + SZH + 2 * SZF);
    int*   deg      = (int*)(ws + SZH + 2 * SZF + SZE);
    float* loopattr = (float*)(deg + NN);
    // zeroed region:
    unsigned long long* combo = (unsigned long long*)(loopattr + NN);
    float* sums1  = (float*)(combo + NN);
    float* sumsq1 = sums1 + HID;
    float* sums2  = sumsq1 + HID;
    float* sumsq2 = sums2 + EMB;
    float* domsum = sumsq2 + EMB;
    size_t zero_bytes = (char*)(domsum + GG * EMB) - (char*)combo;
    // non-zeroed small scratch:
    float* a1 = domsum + GG * EMB;
    float* b1 = a1 + HID;
    float* a2 = b1 + HID;
    float* b2 = a2 + EMB;
    int* gstart = (int*)(b2 + EMB);

    hipMemsetAsync(combo, 0, zero_bytes, stream);

    k_scatter<<<(EE + 255) / 256, 256, 0, stream>>>(ei, ea, combo, epack);
    k_prep<<<(NN + 255) / 256, 256, 0, stream>>>(combo, deg, loopattr, batch, gstart);

    k_gemm1<<<NN / G1R, 256, 0, stream>>>(x, Wl1, bl1, Wr1, br1, xl1h, xr1);
    k_gat1<<<(NN * 64) / 256, 256, 0, stream>>>(loopattr, deg, epack,
                                                xl1h, xr1, We1, att1, bias1, out1);
    k_bnstat<HID><<<256, 256, 0, stream>>>(out1, sums1, sumsq1);
    k_bnfin<HID><<<1, HID, 0, stream>>>(sums1, sumsq1, gamma1, beta1, a1, b1);
    k_gemm2<<<NN / G2R, 256, 0, stream>>>(out1, a1, b1, Wl2, bl2, Wr2, br2, xl2h, xr2);
    k_gat2<<<(NN * 64) / 256, 256, 0, stream>>>(loopattr, deg, epack,
                                                xl2h, xr2, We2, att2, bias2, out2);
    k_bnstat<EMB><<<256, 256, 0, stream>>>(out2, sums2, sumsq2);
    k_bnfin<EMB><<<1, EMB, 0, stream>>>(sums2, sumsq2, gamma2, beta2, a2, b2);
    k_poolA<<<GG * PB, 256, 0, stream>>>(out2, a2, b2, gstart, out_emb, domsum);
    k_logits<<<GG, EMB, 0, stream>>>(domsum, gstart, Wc, bc, out_dom, out_logits);
}

// Round 16
// 437.419 us; speedup vs baseline: 1.0073x; 1.0073x over previous
//
#include <hip/hip_runtime.h>
#include <hip/hip_bf16.h>
#include <math.h>

#define NN 50000
#define EE 800000
#define GG 50
#define FIN 64
#define HID 128
#define EMB 64
#define NCLS 6
#define EPSBN 1e-5f
#define NEG 0.2f
#define MAXD 64   // max in-degree bucket (deg ~ Poisson(16); P(>=64) ~ 1e-55)
#define PB 8      // pool blocks per graph

__device__ __forceinline__ float lrelu(float x){ return fmaxf(x, NEG * x); }
__device__ __forceinline__ float bf16lo(unsigned u){ return __uint_as_float(u << 16); }
__device__ __forceinline__ float bf16hi(unsigned u){ return __uint_as_float(u & 0xffff0000u); }
__device__ __forceinline__ unsigned f2bf_bits(float f){
    unsigned u = __float_as_uint(f);
    return (u + 0x7fffu + ((u >> 16) & 1u)) >> 16;   // RNE
}

// ---- single-pass bucket scatter: 1 atomic/edge ---------------------------
__global__ void k_scatter(const int* __restrict__ ei, const float* __restrict__ ea,
                          unsigned long long* __restrict__ combo,
                          unsigned* __restrict__ epack) {
    int e = blockIdx.x * 256 + threadIdx.x;
    if (e < EE) {
        int d = ei[EE + e];
        int s = ei[e];
        float eaf = ea[e];
        unsigned long long add = (1ULL << 40) | (unsigned long long)(eaf * 1048576.0f);
        unsigned long long old = atomicAdd(&combo[d], add);
        int pos = (int)(old >> 40);
        epack[d * MAXD + pos] = ((unsigned)s << 16) | f2bf_bits(eaf);
    }
}

// decode combo -> deg, loopattr ; graph boundaries from sorted batch
__global__ void k_prep(const unsigned long long* __restrict__ combo,
                       int* __restrict__ deg, float* __restrict__ loopattr,
                       const int* __restrict__ batch, int* __restrict__ gstart) {
    int n = blockIdx.x * 256 + threadIdx.x;
    if (n < NN) {
        unsigned long long c = combo[n];
        int cnt = (int)(c >> 40);
        float easum = (float)(c & ((1ULL << 40) - 1)) * (1.0f / 1048576.0f);
        deg[n] = cnt;
        loopattr[n] = cnt > 0 ? easum / (float)cnt : 0.f;
        int b = batch[n];
        int prev = (n == 0) ? -1 : batch[n - 1];
        for (int g = prev + 1; g <= b; g++) gstart[g] = n;
        if (n == NN - 1) {
            for (int g = b + 1; g <= GG; g++) gstart[g] = NN;
        }
    }
}

// ---- GEMM 1: 16 rows/block, 4x4 register tile ---------------------------
// 256 thr = 64 col-quads (256 out cols: 0..127 Wl->xlh, 128..255 Wr->xr) x 4 row-groups
#define G1R 16
__global__ void k_gemm1(const float* __restrict__ x,
                        const float* __restrict__ Wl, const float* __restrict__ bl,
                        const float* __restrict__ Wr, const float* __restrict__ br,
                        __hip_bfloat16* __restrict__ xlh, float* __restrict__ xr) {
    __shared__ float xs[G1R][FIN];   // 4 KB
    int rb = blockIdx.x * G1R;
    int t = threadIdx.x;  // 256
    {   // stage: one float4 per thread
        int idx4 = t * 4;
        int r = idx4 >> 6, k = idx4 & 63;
        *reinterpret_cast<float4*>(&xs[r][k]) =
            *reinterpret_cast<const float4*>(&x[(rb + r) * FIN + k]);
    }
    __syncthreads();
    int cq = t & 63;          // col-quad
    int rg = t >> 6;          // row-group 0..3 -> rows rg*4..rg*4+3
    bool isL = cq < 32;
    int cc = (isL ? cq : cq - 32) * 4;
    const float* W = isL ? Wl : Wr;
    const float* bb = isL ? bl : br;
    float4 bi = *reinterpret_cast<const float4*>(&bb[cc]);
    float acc[4][4];
#pragma unroll
    for (int r = 0; r < 4; r++) {
        acc[r][0] = bi.x; acc[r][1] = bi.y; acc[r][2] = bi.z; acc[r][3] = bi.w;
    }
    int r0 = rg * 4;
    for (int k = 0; k < FIN; k += 4) {
        float4 hv0 = *reinterpret_cast<const float4*>(&xs[r0 + 0][k]);
        float4 hv1 = *reinterpret_cast<const float4*>(&xs[r0 + 1][k]);
        float4 hv2 = *reinterpret_cast<const float4*>(&xs[r0 + 2][k]);
        float4 hv3 = *reinterpret_cast<const float4*>(&xs[r0 + 3][k]);
        float4 wv0 = *reinterpret_cast<const float4*>(&W[(k + 0) * HID + cc]);
        float4 wv1 = *reinterpret_cast<const float4*>(&W[(k + 1) * HID + cc]);
        float4 wv2 = *reinterpret_cast<const float4*>(&W[(k + 2) * HID + cc]);
        float4 wv3 = *reinterpret_cast<const float4*>(&W[(k + 3) * HID + cc]);
#define ROWFMA(R, HV)                                                          \
        acc[R][0] = fmaf(HV.x, wv0.x, fmaf(HV.y, wv1.x, fmaf(HV.z, wv2.x, fmaf(HV.w, wv3.x, acc[R][0])))); \
        acc[R][1] = fmaf(HV.x, wv0.y, fmaf(HV.y, wv1.y, fmaf(HV.z, wv2.y, fmaf(HV.w, wv3.y, acc[R][1])))); \
        acc[R][2] = fmaf(HV.x, wv0.z, fmaf(HV.y, wv1.z, fmaf(HV.z, wv2.z, fmaf(HV.w, wv3.z, acc[R][2])))); \
        acc[R][3] = fmaf(HV.x, wv0.w, fmaf(HV.y, wv1.w, fmaf(HV.z, wv2.w, fmaf(HV.w, wv3.w, acc[R][3]))));
        ROWFMA(0, hv0) ROWFMA(1, hv1) ROWFMA(2, hv2) ROWFMA(3, hv3)
#undef ROWFMA
    }
    if (isL) {
#pragma unroll
        for (int r = 0; r < 4; r++) {
            ushort4 us;
            us.x = (unsigned short)f2bf_bits(acc[r][0]);
            us.y = (unsigned short)f2bf_bits(acc[r][1]);
            us.z = (unsigned short)f2bf_bits(acc[r][2]);
            us.w = (unsigned short)f2bf_bits(acc[r][3]);
            *reinterpret_cast<ushort4*>(&xlh[(rb + r0 + r) * HID + cc]) = us;
        }
    } else {
#pragma unroll
        for (int r = 0; r < 4; r++) {
            *reinterpret_cast<float4*>(&xr[(rb + r0 + r) * HID + cc]) =
                make_float4(acc[r][0], acc[r][1], acc[r][2], acc[r][3]);
        }
    }
}

// ---- GATv2 layer 1: half-wave, 4 streams/half (8 edges in flight) -------
__global__ void k_gat1(const float* __restrict__ loopattr, const int* __restrict__ deg,
                       const unsigned* __restrict__ epack,
                       const __hip_bfloat16* __restrict__ xlh, const float* __restrict__ xr1,
                       const float* __restrict__ We1, const float* __restrict__ att1,
                       const float* __restrict__ bias1, float* __restrict__ out1) {
    int wid = (blockIdx.x * blockDim.x + threadIdx.x) >> 6;
    int lane = threadIdx.x & 63;
    if (wid >= NN) return;
    int n = wid;
    int half = lane >> 5;        // 0 or 1
    int cl   = lane & 31;        // channel-lane
    int c0   = 4 * cl;           // channels c0..c0+3 ; head = cl>>2
    float4 xrv = *reinterpret_cast<const float4*>(&xr1[n * HID + c0]);
    float4 we  = *reinterpret_cast<const float4*>(&We1[c0]);
    float4 at  = *reinterpret_cast<const float4*>(&att1[c0]);
    float la = loopattr[n];
    int beg = n * MAXD, end = beg + deg[n];

    float s0 = 0.f, a00 = 0.f, a01 = 0.f, a02 = 0.f, a03 = 0.f;
    float s1 = 0.f, a10 = 0.f, a11 = 0.f, a12 = 0.f, a13 = 0.f;
    float s2 = 0.f, a20 = 0.f, a21 = 0.f, a22 = 0.f, a23 = 0.f;
    float s3 = 0.f, a30 = 0.f, a31 = 0.f, a32 = 0.f, a33 = 0.f;

#define UPD1(U, EA, SS, A0, A1, A2, A3)                                       \
    {                                                                          \
        float x0 = bf16lo((U).x), x1 = bf16hi((U).x);                          \
        float x2 = bf16lo((U).y), x3 = bf16hi((U).y);                          \
        float g0 = lrelu(x0 + fmaf(EA, we.x, xrv.x));                          \
        float g1 = lrelu(x1 + fmaf(EA, we.y, xrv.y));                          \
        float g2 = lrelu(x2 + fmaf(EA, we.z, xrv.z));                          \
        float g3 = lrelu(x3 + fmaf(EA, we.w, xrv.w));                          \
        float part = g0 * at.x + g1 * at.y + g2 * at.z + g3 * at.w;            \
        part += __shfl_xor(part, 1);                                           \
        part += __shfl_xor(part, 2);                                           \
        float p = __expf(part);                                                \
        SS += p;                                                               \
        A0 = fmaf(x0, p, A0);                                                  \
        A1 = fmaf(x1, p, A1);                                                  \
        A2 = fmaf(x2, p, A2);                                                  \
        A3 = fmaf(x3, p, A3);                                                  \
    }

    for (int base = beg; base < end; base += 8) {
        int i = base + half * 4;                      // 16B-aligned (MAXD=64)
        uint4 q = *reinterpret_cast<const uint4*>(&epack[i]);  // always in padded row
        bool b0 = i + 0 < end, b1 = i + 1 < end, b2 = i + 2 < end, b3 = i + 3 < end;
        uint2 u0 = b0 ? *reinterpret_cast<const uint2*>(&xlh[(q.x >> 16) * HID + c0]) : make_uint2(0, 0);
        uint2 u1 = b1 ? *reinterpret_cast<const uint2*>(&xlh[(q.y >> 16) * HID + c0]) : make_uint2(0, 0);
        uint2 u2 = b2 ? *reinterpret_cast<const uint2*>(&xlh[(q.z >> 16) * HID + c0]) : make_uint2(0, 0);
        uint2 u3 = b3 ? *reinterpret_cast<const uint2*>(&xlh[(q.w >> 16) * HID + c0]) : make_uint2(0, 0);
        if (b0) UPD1(u0, bf16lo(q.x), s0, a00, a01, a02, a03);
        if (b1) UPD1(u1, bf16lo(q.y), s1, a10, a11, a12, a13);
        if (b2) UPD1(u2, bf16lo(q.z), s2, a20, a21, a22, a23);
        if (b3) UPD1(u3, bf16lo(q.w), s3, a30, a31, a32, a33);
    }
    if (half == 1) {   // self-loop in half B, stream 0
        uint2 u = *reinterpret_cast<const uint2*>(&xlh[n * HID + c0]);
        UPD1(u, la, s0, a00, a01, a02, a03);
    }
#undef UPD1

    // merge 4 streams + cross-half (plain sums)
    s0 += s1 + s2 + s3;
    a00 += a10 + a20 + a30;
    a01 += a11 + a21 + a31;
    a02 += a12 + a22 + a32;
    a03 += a13 + a23 + a33;
    s0  += __shfl_xor(s0, 32);
    a00 += __shfl_xor(a00, 32);
    a01 += __shfl_xor(a01, 32);
    a02 += __shfl_xor(a02, 32);
    a03 += __shfl_xor(a03, 32);
    if (half == 0) {
        float4 bi = *reinterpret_cast<const float4*>(&bias1[c0]);
        float inv = 1.f / s0;
        float4 o = make_float4(a00 * inv + bi.x, a01 * inv + bi.y,
                               a02 * inv + bi.z, a03 * inv + bi.w);
        *reinterpret_cast<float4*>(&out1[n * HID + c0]) = o;
    }
}

// ---- BatchNorm stats (float4 channels) + finalize -----------------------
template <int CH>
__global__ void k_bnstat(const float* __restrict__ xin, float* __restrict__ sums,
                         float* __restrict__ sumsq) {
    constexpr int CG = CH / 4;
    constexpr int RPI = 256 / CG;
    int t = threadIdx.x;
    int cg = t % CG;
    int rl = t / CG;
    float4 s = make_float4(0.f, 0.f, 0.f, 0.f);
    float4 q = make_float4(0.f, 0.f, 0.f, 0.f);
    for (int r = blockIdx.x * RPI + rl; r < NN; r += gridDim.x * RPI) {
        float4 v = *reinterpret_cast<const float4*>(&xin[r * CH + cg * 4]);
        s.x += v.x; s.y += v.y; s.z += v.z; s.w += v.w;
        q.x = fmaf(v.x, v.x, q.x); q.y = fmaf(v.y, v.y, q.y);
        q.z = fmaf(v.z, v.z, q.z); q.w = fmaf(v.w, v.w, q.w);
    }
    __shared__ float4 sh[256], shq[256];
    sh[t] = s; shq[t] = q;
    __syncthreads();
    if (t < CG) {
        float4 ts = make_float4(0.f, 0.f, 0.f, 0.f);
        float4 tq = make_float4(0.f, 0.f, 0.f, 0.f);
        for (int i = t; i < 256; i += CG) {
            float4 a = sh[i], b = shq[i];
            ts.x += a.x; ts.y += a.y; ts.z += a.z; ts.w += a.w;
            tq.x += b.x; tq.y += b.y; tq.z += b.z; tq.w += b.w;
        }
        atomicAdd(&sums[t * 4 + 0], ts.x);
        atomicAdd(&sums[t * 4 + 1], ts.y);
        atomicAdd(&sums[t * 4 + 2], ts.z);
        atomicAdd(&sums[t * 4 + 3], ts.w);
        atomicAdd(&sumsq[t * 4 + 0], tq.x);
        atomicAdd(&sumsq[t * 4 + 1], tq.y);
        atomicAdd(&sumsq[t * 4 + 2], tq.z);
        atomicAdd(&sumsq[t * 4 + 3], tq.w);
    }
}

template <int CH>
__global__ void k_bnfin(const float* __restrict__ sums, const float* __restrict__ sumsq,
                        const float* __restrict__ gamma, const float* __restrict__ beta,
                        float* __restrict__ a, float* __restrict__ b) {
    int c = threadIdx.x;
    if (c < CH) {
        float mean = sums[c] / (float)NN;
        float var  = sumsq[c] / (float)NN - mean * mean;
        float rs = rsqrtf(var + EPSBN);
        float aa = gamma[c] * rs;
        a[c] = aa;
        b[c] = beta[c] - mean * aa;
    }
}

// ---- GEMM 2: 32 rows/block, 4x4 register tile, fused BN+ReLU input ------
// 256 thr = 32 col-quads (128 out cols: 0..63 Wl->xlh, 64..127 Wr->xr2) x 8 row-groups
#define G2R 32
__global__ void k_gemm2(const float* __restrict__ out1, const float* __restrict__ a1,
                        const float* __restrict__ b1,
                        const float* __restrict__ Wl, const float* __restrict__ bl,
                        const float* __restrict__ Wr, const float* __restrict__ br,
                        __hip_bfloat16* __restrict__ xlh, float* __restrict__ xr2) {
    __shared__ float hs[G2R][HID];   // 16 KB
    int rb = blockIdx.x * G2R;
    int t = threadIdx.x;  // 256
    for (int i = t; i < G2R * HID / 4; i += 256) {
        int idx4 = i * 4;
        int r = idx4 >> 7, k = idx4 & 127;
        float4 v;
        if (rb + r < NN) {
            v = *reinterpret_cast<const float4*>(&out1[(rb + r) * HID + k]);
            float4 av = *reinterpret_cast<const float4*>(&a1[k]);
            float4 bv = *reinterpret_cast<const float4*>(&b1[k]);
            v.x = fmaxf(fmaf(v.x, av.x, bv.x), 0.f);
            v.y = fmaxf(fmaf(v.y, av.y, bv.y), 0.f);
            v.z = fmaxf(fmaf(v.z, av.z, bv.z), 0.f);
            v.w = fmaxf(fmaf(v.w, av.w, bv.w), 0.f);
        } else {
            v = make_float4(0.f, 0.f, 0.f, 0.f);
        }
        *reinterpret_cast<float4*>(&hs[r][k]) = v;
    }
    __syncthreads();
    int cq = t & 31;          // col-quad (128 cols)
    int rg = t >> 5;          // row-group 0..7
    bool isL = cq < 16;
    int cc = (isL ? cq : cq - 16) * 4;
    const float* W = isL ? Wl : Wr;
    const float* bb = isL ? bl : br;
    float4 bi = *reinterpret_cast<const float4*>(&bb[cc]);
    float acc[4][4];
#pragma unroll
    for (int r = 0; r < 4; r++) {
        acc[r][0] = bi.x; acc[r][1] = bi.y; acc[r][2] = bi.z; acc[r][3] = bi.w;
    }
    int r0 = rg * 4;
    for (int k = 0; k < HID; k += 4) {
        float4 hv0 = *reinterpret_cast<const float4*>(&hs[r0 + 0][k]);
        float4 hv1 = *reinterpret_cast<const float4*>(&hs[r0 + 1][k]);
        float4 hv2 = *reinterpret_cast<const float4*>(&hs[r0 + 2][k]);
        float4 hv3 = *reinterpret_cast<const float4*>(&hs[r0 + 3][k]);
        float4 wv0 = *reinterpret_cast<const float4*>(&W[(k + 0) * EMB + cc]);
        float4 wv1 = *reinterpret_cast<const float4*>(&W[(k + 1) * EMB + cc]);
        float4 wv2 = *reinterpret_cast<const float4*>(&W[(k + 2) * EMB + cc]);
        float4 wv3 = *reinterpret_cast<const float4*>(&W[(k + 3) * EMB + cc]);
#define ROWFMA(R, HV)                                                          \
        acc[R][0] = fmaf(HV.x, wv0.x, fmaf(HV.y, wv1.x, fmaf(HV.z, wv2.x, fmaf(HV.w, wv3.x, acc[R][0])))); \
        acc[R][1] = fmaf(HV.x, wv0.y, fmaf(HV.y, wv1.y, fmaf(HV.z, wv2.y, fmaf(HV.w, wv3.y, acc[R][1])))); \
        acc[R][2] = fmaf(HV.x, wv0.z, fmaf(HV.y, wv1.z, fmaf(HV.z, wv2.z, fmaf(HV.w, wv3.z, acc[R][2])))); \
        acc[R][3] = fmaf(HV.x, wv0.w, fmaf(HV.y, wv1.w, fmaf(HV.z, wv2.w, fmaf(HV.w, wv3.w, acc[R][3]))));
        ROWFMA(0, hv0) ROWFMA(1, hv1) ROWFMA(2, hv2) ROWFMA(3, hv3)
#undef ROWFMA
    }
    if (isL) {
#pragma unroll
        for (int r = 0; r < 4; r++) {
            if (rb + r0 + r < NN) {
                ushort4 us;
                us.x = (unsigned short)f2bf_bits(acc[r][0]);
                us.y = (unsigned short)f2bf_bits(acc[r][1]);
                us.z = (unsigned short)f2bf_bits(acc[r][2]);
                us.w = (unsigned short)f2bf_bits(acc[r][3]);
                *reinterpret_cast<ushort4*>(&xlh[(rb + r0 + r) * EMB + cc]) = us;
            }
        }
    } else {
#pragma unroll
        for (int r = 0; r < 4; r++) {
            if (rb + r0 + r < NN) {
                *reinterpret_cast<float4*>(&xr2[(rb + r0 + r) * EMB + cc]) =
                    make_float4(acc[r][0], acc[r][1], acc[r][2], acc[r][3]);
            }
        }
    }
}

// ---- GATv2 layer 2: half-wave, 4 streams/half (8 edges in flight) -------
__global__ void k_gat2(const float* __restrict__ loopattr, const int* __restrict__ deg,
                       const unsigned* __restrict__ epack,
                       const __hip_bfloat16* __restrict__ xlh, const float* __restrict__ xr2,
                       const float* __restrict__ We2, const float* __restrict__ att2,
                       const float* __restrict__ bias2, float* __restrict__ out2) {
    int wid = (blockIdx.x * blockDim.x + threadIdx.x) >> 6;
    int lane = threadIdx.x & 63;
    if (wid >= NN) return;
    int n = wid;
    int half = lane >> 5;
    int cl   = lane & 31;
    int c0   = 2 * cl;
    float2 xrv = *reinterpret_cast<const float2*>(&xr2[n * EMB + c0]);
    float2 we  = *reinterpret_cast<const float2*>(&We2[c0]);
    float2 at  = *reinterpret_cast<const float2*>(&att2[c0]);
    float la = loopattr[n];
    int beg = n * MAXD, end = beg + deg[n];

    float s0 = 0.f, a00 = 0.f, a01 = 0.f;
    float s1 = 0.f, a10 = 0.f, a11 = 0.f;
    float s2 = 0.f, a20 = 0.f, a21 = 0.f;
    float s3 = 0.f, a30 = 0.f, a31 = 0.f;

#define UPD2(U, EA, SS, A0, A1)                                               \
    {                                                                          \
        float x0 = bf16lo(U), x1 = bf16hi(U);                                  \
        float g0 = lrelu(x0 + fmaf(EA, we.x, xrv.x));                          \
        float g1 = lrelu(x1 + fmaf(EA, we.y, xrv.y));                          \
        float part = g0 * at.x + g1 * at.y;                                    \
        part += __shfl_xor(part, 1);                                           \
        part += __shfl_xor(part, 2);                                           \
        part += __shfl_xor(part, 4);                                           \
        part += __shfl_xor(part, 8);                                           \
        part += __shfl_xor(part, 16);                                          \
        float p = __expf(part);                                                \
        SS += p;                                                               \
        A0 = fmaf(x0, p, A0);                                                  \
        A1 = fmaf(x1, p, A1);                                                  \
    }

    for (int base = beg; base < end; base += 8) {
        int i = base + half * 4;
        uint4 q = *reinterpret_cast<const uint4*>(&epack[i]);
        bool b0 = i + 0 < end, b1 = i + 1 < end, b2 = i + 2 < end, b3 = i + 3 < end;
        unsigned u0 = b0 ? *reinterpret_cast<const unsigned*>(&xlh[(q.x >> 16) * EMB + c0]) : 0u;
        unsigned u1 = b1 ? *reinterpret_cast<const unsigned*>(&xlh[(q.y >> 16) * EMB + c0]) : 0u;
        unsigned u2 = b2 ? *reinterpret_cast<const unsigned*>(&xlh[(q.z >> 16) * EMB + c0]) : 0u;
        unsigned u3 = b3 ? *reinterpret_cast<const unsigned*>(&xlh[(q.w >> 16) * EMB + c0]) : 0u;
        if (b0) UPD2(u0, bf16lo(q.x), s0, a00, a01);
        if (b1) UPD2(u1, bf16lo(q.y), s1, a10, a11);
        if (b2) UPD2(u2, bf16lo(q.z), s2, a20, a21);
        if (b3) UPD2(u3, bf16lo(q.w), s3, a30, a31);
    }
    if (half == 1) {   // self-loop in half B, stream 0
        unsigned u = *reinterpret_cast<const unsigned*>(&xlh[n * EMB + c0]);
        UPD2(u, la, s0, a00, a01);
    }
#undef UPD2

    s0 += s1 + s2 + s3;
    a00 += a10 + a20 + a30;
    a01 += a11 + a21 + a31;
    s0  += __shfl_xor(s0, 32);
    a00 += __shfl_xor(a00, 32);
    a01 += __shfl_xor(a01, 32);
    if (half == 0) {
        float inv = 1.f / s0;
        float2 o = make_float2(a00 * inv + bias2[c0], a01 * inv + bias2[c0 + 1]);
        *reinterpret_cast<float2*>(&out2[n * EMB + c0]) = o;
    }
}

// ---- fused BN-apply + ReLU + node_emb write + pool partial sums ----------
__global__ void k_poolA(const float* __restrict__ out2, const float* __restrict__ a2,
                        const float* __restrict__ b2, const int* __restrict__ gstart,
                        float* __restrict__ nodeemb, float* __restrict__ domsum) {
    int g = blockIdx.x / PB;
    int sb = blockIdx.x % PB;
    int t = threadIdx.x;  // 256
    int c = t & 63, rl = t >> 6;
    int beg = gstart[g], end = gstart[g + 1];
    float s = 0.f;
    for (int r = beg + sb * 4 + rl; r < end; r += PB * 4) {
        float v = out2[r * EMB + c] * a2[c] + b2[c];
        v = v > 0.f ? v : 0.f;
        nodeemb[r * EMB + c] = v;
        s += v;
    }
    __shared__ float sh[256];
    sh[t] = s;
    __syncthreads();
    if (t < EMB) {
        float tot = sh[t] + sh[t + 64] + sh[t + 128] + sh[t + 192];
        atomicAdd(&domsum[g * EMB + t], tot);
    }
}

__global__ void k_logits(const float* __restrict__ domsum, const int* __restrict__ gstart,
                         const float* __restrict__ Wc, const float* __restrict__ bc,
                         float* __restrict__ dom, float* __restrict__ logits) {
    int g = blockIdx.x;   // 50 blocks x 64 threads
    int t = threadIdx.x;
    __shared__ float dsh[EMB];
    float cf = (float)(gstart[g + 1] - gstart[g]);
    if (cf < 1.f) cf = 1.f;
    float d = domsum[g * EMB + t] / cf;
    dsh[t] = d;
    dom[g * EMB + t] = d;
    __syncthreads();
    if (t < NCLS) {
        float acc = bc[t];
        for (int k = 0; k < EMB; k++) acc += dsh[k] * Wc[k * NCLS + t];
        logits[g * NCLS + t] = acc;
    }
}

extern "C" void kernel_launch(void* const* d_in, const int* in_sizes, int n_in,
                              void* d_out, int out_size, void* d_ws, size_t ws_size,
                              hipStream_t stream) {
    const float* x     = (const float*)d_in[0];
    const int*   ei    = (const int*)d_in[1];
    const float* ea    = (const float*)d_in[2];
    const int*   batch = (const int*)d_in[3];
    const float* Wl1 = (const float*)d_in[4];
    const float* bl1 = (const float*)d_in[5];
    const float* Wr1 = (const float*)d_in[6];
    const float* br1 = (const float*)d_in[7];
    const float* We1 = (const float*)d_in[8];
    const float* att1 = (const float*)d_in[9];
    const float* bias1 = (const float*)d_in[10];
    const float* Wl2 = (const float*)d_in[11];
    const float* bl2 = (const float*)d_in[12];
    const float* Wr2 = (const float*)d_in[13];
    const float* br2 = (const float*)d_in[14];
    const float* We2 = (const float*)d_in[15];
    const float* att2 = (const float*)d_in[16];
    const float* bias2 = (const float*)d_in[17];
    const float* gamma1 = (const float*)d_in[18];
    const float* beta1  = (const float*)d_in[19];
    const float* gamma2 = (const float*)d_in[20];
    const float* beta2  = (const float*)d_in[21];
    const float* Wc = (const float*)d_in[22];
    const float* bc = (const float*)d_in[23];

    float* out_logits = (float*)d_out;                 // [50,6]
    float* out_dom    = out_logits + GG * NCLS;        // [50,64]
    float* out_emb    = out_dom + GG * EMB;            // [50000,64]

    char* ws = (char*)d_ws;
    const size_t SZF = (size_t)NN * HID * sizeof(float);           // 25.6 MB
    const size_t SZH = (size_t)NN * HID * sizeof(__hip_bfloat16);  // 12.8 MB
    const size_t SZE = (size_t)NN * MAXD * sizeof(unsigned);       // 12.8 MB
    __hip_bfloat16* xl1h = (__hip_bfloat16*)(ws);
    float* xr1  = (float*)(ws + SZH);
    float* out1 = (float*)(ws + SZH + SZF);
    __hip_bfloat16* xl2h = xl1h;   // k_gemm2 runs after k_gat1 (last reader of xl1h)
    float* xr2  = xr1;             // k_gemm2 runs after k_gat1 (last reader of xr1)
    float* out2 = out1;            // k_gat2 runs after k_gemm2 (last reader of out1)
    unsigned* epack = (unsigned*)(ws + SZH + 2 * SZF);
    int*   deg      = (int*)(ws + SZH + 2 * SZF + SZE);
    float* loopattr = (float*)(deg + NN);
    // zeroed region:
    unsigned long long* combo = (unsigned long long*)(loopattr + NN);
    float* sums1  = (float*)(combo + NN);
    float* sumsq1 = sums1 + HID;
    float* sums2  = sumsq1 + HID;
    float* sumsq2 = sums2 + EMB;
    float* domsum = sumsq2 + EMB;
    size_t zero_bytes = (char*)(domsum + GG * EMB) - (char*)combo;
    // non-zeroed small scratch:
    float* a1 = domsum + GG * EMB;
    float* b1 = a1 + HID;
    float* a2 = b1 + HID;
    float* b2 = a2 + EMB;
    int* gstart = (int*)(b2 + EMB);

    hipMemsetAsync(combo, 0, zero_bytes, stream);

    k_scatter<<<(EE + 255) / 256, 256, 0, stream>>>(ei, ea, combo, epack);
    k_prep<<<(NN + 255) / 256, 256, 0, stream>>>(combo, deg, loopattr, batch, gstart);

    k_gemm1<<<NN / G1R, 256, 0, stream>>>(x, Wl1, bl1, Wr1, br1, xl1h, xr1);
    k_gat1<<<(NN * 64) / 256, 256, 0, stream>>>(loopattr, deg, epack,
                                                xl1h, xr1, We1, att1, bias1, out1);
    k_bnstat<HID><<<256, 256, 0, stream>>>(out1, sums1, sumsq1);
    k_bnfin<HID><<<1, HID, 0, stream>>>(sums1, sumsq1, gamma1, beta1, a1, b1);
    k_gemm2<<<(NN + G2R - 1) / G2R, 256, 0, stream>>>(out1, a1, b1, Wl2, bl2, Wr2, br2, xl2h, xr2);
    k_gat2<<<(NN * 64) / 256, 256, 0, stream>>>(loopattr, deg, epack,
                                                xl2h, xr2, We2, att2, bias2, out2);
    k_bnstat<EMB><<<256, 256, 0, stream>>>(out2, sums2, sumsq2);
    k_bnfin<EMB><<<1, EMB, 0, stream>>>(sums2, sumsq2, gamma2, beta2, a2, b2);
    k_poolA<<<GG * PB, 256, 0, stream>>>(out2, a2, b2, gstart, out_emb, domsum);
    k_logits<<<GG, EMB, 0, stream>>>(domsum, gstart, Wc, bc, out_dom, out_logits);
}